// Round 1
// baseline (801.913 us; speedup 1.0000x reference)
//
#include <hip/hip_runtime.h>
#include <cstdint>
#include <cstddef>

#define N_NODES 100000
#define N_EDGES 1600000
#define GG 64

// ---------------- preprocessing ----------------

__global__ __launch_bounds__(256) void count_kernel(const int* __restrict__ col,
                                                    int* __restrict__ cnt, int E) {
  int e = blockIdx.x * blockDim.x + threadIdx.x;
  if (e < E) atomicAdd(&cnt[col[e]], 1);
}

__global__ __launch_bounds__(256) void scan_block_sums(const int* __restrict__ cnt,
                                                       int* __restrict__ bsums,
                                                       int n, int cpt) {
  __shared__ int sdata[256];
  const int tid = threadIdx.x;
  const int base = (blockIdx.x * 256 + tid) * cpt;
  int s = 0;
  for (int j = 0; j < cpt; ++j) {
    int i = base + j;
    if (i < n) s += cnt[i];
  }
  sdata[tid] = s;
  __syncthreads();
  for (int off = 128; off > 0; off >>= 1) {
    if (tid < off) sdata[tid] += sdata[tid + off];
    __syncthreads();
  }
  if (tid == 0) bsums[blockIdx.x] = sdata[0];
}

__global__ void scan_offsets(int* __restrict__ bsums) {
  if (threadIdx.x == 0 && blockIdx.x == 0) {
    int run = 0;
    for (int b = 0; b < 256; ++b) {
      int v = bsums[b];
      bsums[b] = run;
      run += v;
    }
  }
}

__global__ __launch_bounds__(256) void scan_write(const int* __restrict__ cnt,
                                                  const int* __restrict__ boff,
                                                  int* __restrict__ indptr,
                                                  int* __restrict__ cursor,
                                                  float* __restrict__ dis,
                                                  int n, int cpt, int total) {
  __shared__ int sdata[256];
  const int tid = threadIdx.x;
  const int base = (blockIdx.x * 256 + tid) * cpt;
  int s = 0;
  for (int j = 0; j < cpt; ++j) {
    int i = base + j;
    if (i < n) s += cnt[i];
  }
  sdata[tid] = s;
  __syncthreads();
  for (int off = 1; off < 256; off <<= 1) {
    int v = 0;
    if (tid >= off) v = sdata[tid - off];
    __syncthreads();
    sdata[tid] += v;
    __syncthreads();
  }
  int run = boff[blockIdx.x] + sdata[tid] - s;  // exclusive prefix
  for (int j = 0; j < cpt; ++j) {
    int i = base + j;
    if (i < n) {
      indptr[i] = run;
      cursor[i] = run;
      int cv = cnt[i];
      dis[i] = rsqrtf((float)(cv + 1));  // +1 self loop, deg >= 1 always
      run += cv;
    }
  }
  if (blockIdx.x == 0 && tid == 0) indptr[n] = total;
}

__global__ __launch_bounds__(256) void fill_kernel(const int* __restrict__ row,
                                                   const int* __restrict__ col,
                                                   int* __restrict__ cursor,
                                                   int* __restrict__ csr, int E) {
  int e = blockIdx.x * blockDim.x + threadIdx.x;
  if (e < E) {
    int pos = atomicAdd(&cursor[col[e]], 1);
    csr[pos] = row[e];
  }
}

// ---------------- GEMM: C[n,128] = A[n,128] @ W[128,128] (f32 vector ALU) ----------------

__global__ __launch_bounds__(256) void gemm128(const float* __restrict__ A,
                                               const float* __restrict__ W,
                                               float* __restrict__ C, int n) {
  __shared__ float As[128][132];
  __shared__ float Ws[128][132];
  const int tid = threadIdx.x;
  const int row0 = blockIdx.x * 128;
  const int r = tid >> 5;          // 0..7
  const int c4 = (tid & 31) << 2;  // 0,4,...,124
  for (int p = 0; p < 16; ++p) {
    int rr = r + p * 8;
    *reinterpret_cast<float4*>(&Ws[rr][c4]) =
        *reinterpret_cast<const float4*>(W + rr * 128 + c4);
    int ar = row0 + rr;
    float4 av = make_float4(0.f, 0.f, 0.f, 0.f);
    if (ar < n) av = *reinterpret_cast<const float4*>(A + (size_t)ar * 128 + c4);
    *reinterpret_cast<float4*>(&As[rr][c4]) = av;
  }
  __syncthreads();
  const int ty = tid >> 4, tx = tid & 15;
  const int r0 = ty * 8, c0 = tx * 8;
  float acc[8][8];
#pragma unroll
  for (int i = 0; i < 8; ++i)
#pragma unroll
    for (int j = 0; j < 8; ++j) acc[i][j] = 0.f;

  for (int k4 = 0; k4 < 128; k4 += 4) {
    float4 a[8];
#pragma unroll
    for (int i = 0; i < 8; ++i)
      a[i] = *reinterpret_cast<const float4*>(&As[r0 + i][k4]);
#pragma unroll
    for (int kk = 0; kk < 4; ++kk) {
      float4 w0 = *reinterpret_cast<const float4*>(&Ws[k4 + kk][c0]);
      float4 w1 = *reinterpret_cast<const float4*>(&Ws[k4 + kk][c0 + 4]);
#pragma unroll
      for (int i = 0; i < 8; ++i) {
        float av = (&a[i].x)[kk];
        acc[i][0] = fmaf(av, w0.x, acc[i][0]);
        acc[i][1] = fmaf(av, w0.y, acc[i][1]);
        acc[i][2] = fmaf(av, w0.z, acc[i][2]);
        acc[i][3] = fmaf(av, w0.w, acc[i][3]);
        acc[i][4] = fmaf(av, w1.x, acc[i][4]);
        acc[i][5] = fmaf(av, w1.y, acc[i][5]);
        acc[i][6] = fmaf(av, w1.z, acc[i][6]);
        acc[i][7] = fmaf(av, w1.w, acc[i][7]);
      }
    }
  }
#pragma unroll
  for (int i = 0; i < 8; ++i) {
    int rr = row0 + r0 + i;
    if (rr < n) {
      float4 o0 = make_float4(acc[i][0], acc[i][1], acc[i][2], acc[i][3]);
      float4 o1 = make_float4(acc[i][4], acc[i][5], acc[i][6], acc[i][7]);
      *reinterpret_cast<float4*>(C + (size_t)rr * 128 + c0) = o0;
      *reinterpret_cast<float4*>(C + (size_t)rr * 128 + c0 + 4) = o1;
    }
  }
}

// ---------------- aggregation: O[i] = relu(sum_{e: col=i} T[row]*dis[row]*dis[i] + T[i]*dis[i]^2 + b) ----------------

__global__ __launch_bounds__(256) void agg_kernel(const float* __restrict__ T,
                                                  const int* __restrict__ indptr,
                                                  const int* __restrict__ csr,
                                                  const float* __restrict__ dis,
                                                  const float* __restrict__ bias,
                                                  float* __restrict__ O, int n) {
  const int wid = (blockIdx.x << 2) + (threadIdx.x >> 6);  // one wave per node
  if (wid >= n) return;
  const int lane = threadIdx.x & 63;
  const int c = lane << 1;
  const float di = dis[wid];
  const int e0 = indptr[wid], e1 = indptr[wid + 1];
  float ax = 0.f, ay = 0.f;
  for (int e = e0; e < e1; ++e) {
    int s = csr[e];
    float nrm = dis[s] * di;
    float2 v = *reinterpret_cast<const float2*>(T + (size_t)s * 128 + c);
    ax = fmaf(v.x, nrm, ax);
    ay = fmaf(v.y, nrm, ay);
  }
  float2 sv = *reinterpret_cast<const float2*>(T + (size_t)wid * 128 + c);
  float w = di * di;
  ax = fmaf(sv.x, w, ax);
  ay = fmaf(sv.y, w, ay);
  float2 b = *reinterpret_cast<const float2*>(bias + c);
  float2 o;
  o.x = fmaxf(ax + b.x, 0.f);
  o.y = fmaxf(ay + b.y, 0.f);
  *reinterpret_cast<float2*>(O + (size_t)wid * 128 + c) = o;
}

// ---------------- pooling over sorted batch ids ----------------

__global__ __launch_bounds__(256) void pool_kernel(const float* __restrict__ H,
                                                   const int* __restrict__ batch,
                                                   float* __restrict__ pooled,
                                                   float* __restrict__ cntg, int n) {
  const int tid = threadIdx.x;
  const int c = tid & 127;
  const int half = tid >> 7;  // 0 or 1
  const int base = blockIdx.x * 256;
  float acc = 0.f;
  int cnt = 0;
  int curg = -1;
  for (int rr = half; rr < 256; rr += 2) {
    int rowi = base + rr;
    if (rowi >= n) break;
    int g = batch[rowi];
    if (g != curg) {
      if (curg >= 0) {
        atomicAdd(&pooled[curg * 128 + c], acc);
        if (c == 0) atomicAdd(&cntg[curg], (float)cnt);
      }
      curg = g;
      acc = 0.f;
      cnt = 0;
    }
    acc += H[(size_t)rowi * 128 + c];
    cnt++;
  }
  if (curg >= 0) {
    atomicAdd(&pooled[curg * 128 + c], acc);
    if (c == 0) atomicAdd(&cntg[curg], (float)cnt);
  }
}

__global__ __launch_bounds__(128) void final_kernel(const float* __restrict__ pooled,
                                                    const float* __restrict__ cntg,
                                                    const float* __restrict__ Wp,
                                                    const float* __restrict__ bp,
                                                    float* __restrict__ out) {
  const int g = blockIdx.x;
  const int e = threadIdx.x;
  float inv = 1.0f / fmaxf(cntg[g], 1.0f);
  float acc = 0.f;
  for (int c = 0; c < 128; ++c)
    acc = fmaf(pooled[g * 128 + c], Wp[c * 128 + e], acc);
  out[g * 128 + e] = acc * inv + bp[e];
}

// ---------------- launch ----------------

extern "C" void kernel_launch(void* const* d_in, const int* in_sizes, int n_in,
                              void* d_out, int out_size, void* d_ws, size_t ws_size,
                              hipStream_t stream) {
  const float* x = (const float*)d_in[0];
  const int* eidx = (const int*)d_in[1];
  const int* batch = (const int*)d_in[2];
  const float* W1 = (const float*)d_in[3];
  const float* b1 = (const float*)d_in[4];
  const float* W2 = (const float*)d_in[5];
  const float* b2 = (const float*)d_in[6];
  const float* Wp = (const float*)d_in[7];
  const float* bp = (const float*)d_in[8];

  const int n = N_NODES;
  const int E = N_EDGES;
  const int* row = eidx;      // edge_index[0] = sources
  const int* col = eidx + E;  // edge_index[1] = targets

  char* ws = (char*)d_ws;
  size_t off = 0;
  auto alloc = [&](size_t bytes) {
    void* p = ws + off;
    off = (off + bytes + 255) & ~(size_t)255;
    return p;
  };
  float* A = (float*)alloc((size_t)n * 128 * 4);
  float* B = (float*)alloc((size_t)n * 128 * 4);
  float* dis = (float*)alloc((size_t)n * 4);
  int* indptr = (int*)alloc((size_t)(n + 1) * 4);
  int* cnt_i = (int*)alloc((size_t)n * 4);
  int* cursor = (int*)alloc((size_t)n * 4);
  int* csr = (int*)alloc((size_t)E * 4);
  float* pooled = (float*)alloc((size_t)GG * 128 * 4);
  float* cntg = (float*)alloc((size_t)GG * 4);
  int* bsums = (int*)alloc(256 * 4);
  (void)off;

  hipMemsetAsync(cnt_i, 0, (size_t)n * 4, stream);
  hipMemsetAsync(pooled, 0, (size_t)GG * 128 * 4, stream);
  hipMemsetAsync(cntg, 0, (size_t)GG * 4, stream);

  count_kernel<<<(E + 255) / 256, 256, 0, stream>>>(col, cnt_i, E);
  const int cpt = (n + 65535) / 65536;  // elements per thread for the scan
  scan_block_sums<<<256, 256, 0, stream>>>(cnt_i, bsums, n, cpt);
  scan_offsets<<<1, 64, 0, stream>>>(bsums);
  scan_write<<<256, 256, 0, stream>>>(cnt_i, bsums, indptr, cursor, dis, n, cpt, E);
  fill_kernel<<<(E + 255) / 256, 256, 0, stream>>>(row, col, cursor, csr, E);

  gemm128<<<(n + 127) / 128, 256, 0, stream>>>(x, W1, A, n);
  agg_kernel<<<(n + 3) / 4, 256, 0, stream>>>(A, indptr, csr, dis, b1, B, n);
  gemm128<<<(n + 127) / 128, 256, 0, stream>>>(B, W2, A, n);
  agg_kernel<<<(n + 3) / 4, 256, 0, stream>>>(A, indptr, csr, dis, b2, B, n);

  pool_kernel<<<(n + 255) / 256, 256, 0, stream>>>(B, batch, pooled, cntg, n);
  final_kernel<<<GG, 128, 0, stream>>>(pooled, cntg, Wp, bp, (float*)d_out);
}